// Round 5
// baseline (202.539 us; speedup 1.0000x reference)
//
#include <hip/hip_runtime.h>
#include <hip/hip_bf16.h>

#define CIN 32
#define OCH 64
#define HH  256
#define WW  256
#define HW  (HH * WW)
#define BH  8                 // output rows per block
#define ROWB (258 * CIN * 2)  // 16512 B per LDS row-slot

typedef __bf16 bf16x8 __attribute__((ext_vector_type(8)));
typedef float  f32x4  __attribute__((ext_vector_type(4)));

// Fused 3x3 conv (implicit GEMM, bf16 MFMA), sliding window over h.
// Wave partition: wave owns 8 w-tiles x 32 output channels (2 o-groups) ->
// each LDS B-fragment read by 2 waves. Weights register-resident, bias folded
// into acc init. Per-iter barrier is lgkmcnt-only (raw s_barrier): output
// stores are NOT drained at the barrier; they retire under the next
// iteration's compute phase (T3/T4 counted-drain principle).
// LDS row-slot: w-entry wp (= w+1) is 64 B = 4 chunks of 8 channels; chunk for
// channels sc*8..+7 at slot sc ^ ((w>>1)&3). Writes <=2-way (free); B-reads
// conflict-free (enumerated).
__global__ __launch_bounds__(256, 2) void conv_fused_kernel(
        const float* __restrict__ x, const float* __restrict__ wgt,
        const float* __restrict__ bias, float* __restrict__ out) {
    // chunked XCD swizzle: 512 blocks, each XCD gets 64 consecutive nids
    // (2 full batches) so h-adjacent tiles share halo rows in one L2.
    const int bid = blockIdx.x;
    const int nid = (bid & 7) * 64 + (bid >> 3);
    const int b   = nid >> 5;                    // 0..15
    const int h0  = (nid & 31) * BH;             // 0..248
    const int tid = threadIdx.x;
    const int l   = tid & 63, wid = tid >> 6;
    const int lm  = l & 15,  lh  = l >> 4;
    const int ogb = (wid & 1) * 2;               // o-group base: {0,1} or {2,3}
    const int ntb = (wid >> 1) * 8;              // w-tile base: 0 or 8

    __shared__ __bf16 xs[4][258][CIN];           // 66,048 B ring of 4 row-slots
    char* lds = (char*)&xs[0][0][0];
    const float* xb = x + (size_t)b * CIN * HW;

    // zero the w-pad entries (wp=0 and wp=257) of all 4 slots
    if (tid < 32) {
        const int s = tid >> 3, k = tid & 7;
        const int wp = (k < 4) ? 0 : 257;
        *(f32x4*)(lds + s * ROWB + wp * 64 + (k & 3) * 16) = (f32x4){0, 0, 0, 0};
    }

    // ---- weights inline (L2-hot): af[g][t][j] = w[(ogb+g)*16+lm][(lh*8+j)*9+t]
    bf16x8 af[2][9];
#pragma unroll
    for (int g = 0; g < 2; ++g) {
        const float* wp_ = wgt + (size_t)((ogb + g) * 16 + lm) * 288 + (size_t)lh * 8 * 9;
#pragma unroll
        for (int t = 0; t < 9; ++t)
#pragma unroll
            for (int j = 0; j < 8; ++j)
                af[g][t][j] = (__bf16)wp_[j * 9 + t];
    }
    float bv[2][4];
#pragma unroll
    for (int g = 0; g < 2; ++g)
#pragma unroll
        for (int r = 0; r < 4; ++r)
            bv[g][r] = bias[(ogb + g) * 16 + lh * 4 + r];

    // ---- full staging of one row (prologue)
    auto stage = [&](int row) {
        char* slot = lds + ((row + 1) & 3) * ROWB;
        if (row >= 0 && row < HH) {
            const float* rp = xb + (size_t)row * WW;
#pragma unroll
            for (int wh = 0; wh < 2; ++wh) {
                float2 v[8];
#pragma unroll
                for (int j = 0; j < 8; ++j)
                    v[j] = *(const float2*)(rp + (size_t)(wid * 8 + j) * HW + wh * 128 + 2 * l);
#pragma unroll
                for (int p = 0; p < 2; ++p) {
                    const int w = wh * 128 + 2 * l + p;
                    bf16x8 pk;
#pragma unroll
                    for (int j = 0; j < 8; ++j) pk[j] = (__bf16)(p ? v[j].y : v[j].x);
                    *(bf16x8*)(slot + (w + 1) * 64 + ((wid ^ ((w >> 1) & 3)) << 4)) = pk;
                }
            }
        } else {
#pragma unroll
            for (int wh = 0; wh < 2; ++wh)
#pragma unroll
                for (int p = 0; p < 2; ++p) {
                    const int w = wh * 128 + 2 * l + p;
                    *(f32x4*)(slot + (w + 1) * 64 + ((wid ^ ((w >> 1) & 3)) << 4)) =
                        (f32x4){0, 0, 0, 0};
                }
        }
    };

    stage(h0 - 1); stage(h0); stage(h0 + 1);

    // per-lane swizzled w-entry offsets for the 3 kw taps (nt-independent:
    // (nt*16)>>1 == 0 mod 4; u<0 hits the zero pad so any slot is fine)
    int off[3];
#pragma unroll
    for (int kw = 0; kw < 3; ++kw) {
        const int u = lm + kw - 1;
        const int m = (u < 0) ? 3 : ((u >> 1) & 3);
        off[kw] = (lm + kw) * 64 + ((lh ^ m) << 4);
    }

    __syncthreads();

    for (int i = 0; i < BH; ++i) {
        const int h  = h0 + i;
        const int nr = h + 2;
        const bool ldnext = (i < BH - 1) && (nr < HH);
        const bool zrnext = (i < BH - 1) && (nr >= HH);

        // (1) issue-early: global loads for row h+2 (consumed at step 3)
        float2 v[16];
        if (ldnext) {
            const float* rp = xb + (size_t)nr * WW;
#pragma unroll
            for (int wh = 0; wh < 2; ++wh)
#pragma unroll
                for (int j = 0; j < 8; ++j)
                    v[wh * 8 + j] =
                        *(const float2*)(rp + (size_t)(wid * 8 + j) * HW + wh * 128 + 2 * l);
        }

        // (2) compute output row h from slots (h)&3,(h+1)&3,(h+2)&3
        const char* base[3] = { lds + ((h    ) & 3) * ROWB,
                                lds + ((h + 1) & 3) * ROWB,
                                lds + ((h + 2) & 3) * ROWB };
        f32x4 acc[8][2];
#pragma unroll
        for (int nt = 0; nt < 8; ++nt)
#pragma unroll
            for (int g = 0; g < 2; ++g)
                acc[nt][g] = (f32x4){bv[g][0], bv[g][1], bv[g][2], bv[g][3]};

#pragma unroll
        for (int nt = 0; nt < 8; ++nt)
#pragma unroll
            for (int kh = 0; kh < 3; ++kh)
#pragma unroll
                for (int kw = 0; kw < 3; ++kw) {
                    bf16x8 bf = *(const bf16x8*)(base[kh] + off[kw] + (ntb + nt) * 1024);
                    acc[nt][0] = __builtin_amdgcn_mfma_f32_16x16x32_bf16(
                        af[0][kh * 3 + kw], bf, acc[nt][0], 0, 0, 0);
                    acc[nt][1] = __builtin_amdgcn_mfma_f32_16x16x32_bf16(
                        af[1][kh * 3 + kw], bf, acc[nt][1], 0, 0, 0);
                }

        // (3) write-late: cvt + ds_write row h+2 into slot (h+3)&3
        //     (disjoint from the 3 slots read above)
        if (ldnext) {
            char* slot = lds + ((nr + 1) & 3) * ROWB;
#pragma unroll
            for (int wh = 0; wh < 2; ++wh)
#pragma unroll
                for (int p = 0; p < 2; ++p) {
                    const int w = wh * 128 + 2 * l + p;
                    bf16x8 pk;
#pragma unroll
                    for (int j = 0; j < 8; ++j)
                        pk[j] = (__bf16)(p ? v[wh * 8 + j].y : v[wh * 8 + j].x);
                    *(bf16x8*)(slot + (w + 1) * 64 + ((wid ^ ((w >> 1) & 3)) << 4)) = pk;
                }
        } else if (zrnext) {
            char* slot = lds + ((nr + 1) & 3) * ROWB;
#pragma unroll
            for (int wh = 0; wh < 2; ++wh)
#pragma unroll
                for (int p = 0; p < 2; ++p) {
                    const int w = wh * 128 + 2 * l + p;
                    *(f32x4*)(slot + (w + 1) * 64 + ((wid ^ ((w >> 1) & 3)) << 4)) =
                        (f32x4){0, 0, 0, 0};
                }
        }

        // (4) LDS-only barrier: ds_writes visible, stores NOT drained
        if (i < BH - 1) {
            __builtin_amdgcn_sched_barrier(0);
            asm volatile("s_waitcnt lgkmcnt(0)" ::: "memory");
            __builtin_amdgcn_s_barrier();
            __builtin_amdgcn_sched_barrier(0);
        }

        // (5) store row h AFTER the barrier: retires under next iter's compute
        float* outb = out + (size_t)b * OCH * HW + (size_t)h * WW;
#pragma unroll
        for (int nt = 0; nt < 8; ++nt)
#pragma unroll
            for (int g = 0; g < 2; ++g)
#pragma unroll
                for (int r2 = 0; r2 < 4; ++r2)
                    outb[(size_t)((ogb + g) * 16 + lh * 4 + r2) * HW +
                         (ntb + nt) * 16 + lm] = acc[nt][g][r2];
    }
}

extern "C" void kernel_launch(void* const* d_in, const int* in_sizes, int n_in,
                              void* d_out, int out_size, void* d_ws, size_t ws_size,
                              hipStream_t stream) {
    const float* x    = (const float*)d_in[0];
    const float* w    = (const float*)d_in[1];
    const float* bias = (const float*)d_in[2];
    float* out = (float*)d_out;

    hipLaunchKernelGGL(conv_fused_kernel, dim3(16 * (HH / BH)), dim3(256), 0, stream,
                       x, w, bias, out);
}

// Round 6
// 115.212 us; speedup vs baseline: 1.7580x; 1.7580x over previous
//
#include <hip/hip_runtime.h>
#include <hip/hip_bf16.h>

#define CIN  32
#define OCH  64
#define HH   256
#define WW   256
#define HW   (HH * WW)
#define BH   8                // output rows per block
#define NENT 130              // w-entries per slot: 128 + 2 halo columns
#define ROWB (NENT * 64)      // 8320 B per LDS row-slot

typedef __bf16 bf16x8 __attribute__((ext_vector_type(8)));
typedef float  f32x4  __attribute__((ext_vector_type(4)));

// Fused 3x3 conv (implicit GEMM, bf16 MFMA), sliding window over h, w-split.
// Block = (b, 8-row h-tile, 128-w half): LDS 33,280 B -> 4 blocks/CU,
// 16 waves/CU (vs r3's 8) so HBM stays busy through each block's barrier.
// Wave owns o-group wid (af[9] = 36 VGPR, no spill; r4/r5's af[2][9] spilled:
// WRITE_SIZE +80-100MB scratch evictions). Stores pipelined to top of next
// iter so the barrier's vmcnt drain sees long-retired stores.
// LDS w-entry (keyed on GLOBAL w): 64 B = 4 chunks of 8 ch; chunk sc at
// sc ^ ((w>>1)&3), w<0 -> 3. B-reads: 64 lanes cover a contiguous 1 KiB span
// bijectively (conflict-free, enumerated).
__global__ __launch_bounds__(256, 4) void conv_fused_kernel(
        const float* __restrict__ x, const float* __restrict__ wgt,
        const float* __restrict__ bias, float* __restrict__ out) {
    // chunked XCD swizzle: 1024 blocks, 128 consecutive nids per XCD; adjacent
    // nids share halo rows / h-neighbors -> L2 locality within an XCD.
    const int bid = blockIdx.x;
    const int nid = (bid & 7) * 128 + (bid >> 3);
    const int wh  = nid & 1;                 // w-half
    const int ht  = (nid >> 1) & 31;         // h-tile
    const int b   = nid >> 6;                // batch
    const int wbase = wh * 128;
    const int h0    = ht * BH;
    const int tid = threadIdx.x;
    const int l   = tid & 63, wid = tid >> 6;
    const int lm  = l & 15,  lh  = l >> 4;

    __shared__ __bf16 xs[4][NENT][CIN];      // 33,280 B ring of 4 row-slots
    char* lds = (char*)&xs[0][0][0];
    const float* xb = x + (size_t)b * CIN * HW;

    // ---- weights (L2-hot): af[t][j] = w[wid*16+lm][(lh*8+j)*9 + t]
    bf16x8 af[9];
    {
        const float* wp_ = wgt + (size_t)(wid * 16 + lm) * 288 + (size_t)lh * 8 * 9;
#pragma unroll
        for (int t = 0; t < 9; ++t)
#pragma unroll
            for (int j = 0; j < 8; ++j)
                af[t][j] = (__bf16)wp_[j * 9 + t];
    }
    float bv[4];
#pragma unroll
    for (int r = 0; r < 4; ++r) bv[r] = bias[wid * 16 + lh * 4 + r];

    // ---- stage one full row (load+cvt+write; prologue only)
    auto stageFull = [&](int row) {
        char* slot = lds + ((row + 1) & 3) * ROWB;
        const bool rok = (row >= 0) && (row < HH);
        const float* rp = xb + (size_t)row * WW;
        float2 v[8];
#pragma unroll
        for (int j = 0; j < 8; ++j)
            v[j] = rok ? *(const float2*)(rp + (size_t)(wid * 8 + j) * HW + wbase + 2 * l)
                       : make_float2(0.f, 0.f);
#pragma unroll
        for (int p = 0; p < 2; ++p) {
            const int w = wbase + 2 * l + p;
            bf16x8 pk;
#pragma unroll
            for (int j = 0; j < 8; ++j) pk[j] = (__bf16)(p ? v[j].y : v[j].x);
            *(bf16x8*)(slot + (2 * l + p + 1) * 64 + ((wid ^ ((w >> 1) & 3)) << 4)) = pk;
        }
        if (tid < 64) {      // 2 halo columns: 32 ch x 1 w each
            const int side = l >> 5, ch = l & 31;
            const int wg = wbase + (side ? 128 : -1);
            const bool wok = rok && (wg >= 0) && (wg < WW);
            const float hval = wok ? rp[(size_t)ch * HW + wg] : 0.f;
            const int m = (wg < 0) ? 3 : ((wg >> 1) & 3);
            const int e = side ? 129 : 0;
            *(__bf16*)(slot + e * 64 + (((ch >> 3) ^ m) << 4) + (ch & 7) * 2) =
                (__bf16)hval;
        }
    };

    stageFull(h0 - 1); stageFull(h0); stageFull(h0 + 1);

    // per-lane swizzled entry offsets (global-w keyed; nt-independent since
    // nt*16>>1 == 0 mod 4; u<0 only at wbase=0 left pad)
    int off[3];
#pragma unroll
    for (int kw = 0; kw < 3; ++kw) {
        const int u = wbase + lm + kw - 1;
        const int m = (u < 0) ? 3 : ((u >> 1) & 3);
        off[kw] = (lm + kw) * 64 + ((lh ^ m) << 4);
    }

    __syncthreads();

    f32x4 acc[8];
    for (int i = 0; i < BH; ++i) {
        const int h = h0 + i;

        // (0) store row h-1 (issued just after barrier; drains at NEXT barrier,
        //     a full compute phase later)
        if (i > 0) {
            float* outb = out + (size_t)b * OCH * HW + (size_t)(h - 1) * WW + wbase;
#pragma unroll
            for (int nt = 0; nt < 8; ++nt)
#pragma unroll
                for (int r2 = 0; r2 < 4; ++r2)
                    outb[(size_t)(wid * 16 + lh * 4 + r2) * HW + nt * 16 + lm] =
                        acc[nt][r2];
        }

        // (1) acc init with bias folded
#pragma unroll
        for (int nt = 0; nt < 8; ++nt)
            acc[nt] = (f32x4){bv[0], bv[1], bv[2], bv[3]};

        // (2) issue-early loads for row h+2
        const int nr = h + 2;
        const bool havenext = (i < BH - 1);
        const bool rok2 = havenext && (nr < HH);
        float2 v[8];
        float hval = 0.f;
#pragma unroll
        for (int j = 0; j < 8; ++j) v[j] = make_float2(0.f, 0.f);
        if (rok2) {
            const float* rp = xb + (size_t)nr * WW;
#pragma unroll
            for (int j = 0; j < 8; ++j)
                v[j] = *(const float2*)(rp + (size_t)(wid * 8 + j) * HW + wbase + 2 * l);
            if (tid < 64) {
                const int side = l >> 5;
                const int wg = wbase + (side ? 128 : -1);
                if (wg >= 0 && wg < WW)
                    hval = (xb + (size_t)nr * WW)[(size_t)(l & 31) * HW + wg];
            }
        }

        // (3) MFMA: output row h from slots (h)&3,(h+1)&3,(h+2)&3
        const char* b0 = lds + ((h    ) & 3) * ROWB;
        const char* b1 = lds + ((h + 1) & 3) * ROWB;
        const char* b2 = lds + ((h + 2) & 3) * ROWB;
#pragma unroll
        for (int nt = 0; nt < 8; ++nt) {
#pragma unroll
            for (int kw = 0; kw < 3; ++kw) {
                bf16x8 f0 = *(const bf16x8*)(b0 + off[kw] + nt * 1024);
                acc[nt] = __builtin_amdgcn_mfma_f32_16x16x32_bf16(af[kw], f0, acc[nt], 0, 0, 0);
                bf16x8 f1 = *(const bf16x8*)(b1 + off[kw] + nt * 1024);
                acc[nt] = __builtin_amdgcn_mfma_f32_16x16x32_bf16(af[3 + kw], f1, acc[nt], 0, 0, 0);
                bf16x8 f2 = *(const bf16x8*)(b2 + off[kw] + nt * 1024);
                acc[nt] = __builtin_amdgcn_mfma_f32_16x16x32_bf16(af[6 + kw], f2, acc[nt], 0, 0, 0);
            }
        }

        // (4) write-late: cvt + ds_write row h+2 into slot (h+3)&3
        if (havenext) {
            char* slot = lds + ((nr + 1) & 3) * ROWB;
#pragma unroll
            for (int p = 0; p < 2; ++p) {
                const int w = wbase + 2 * l + p;
                bf16x8 pk;
#pragma unroll
                for (int j = 0; j < 8; ++j) pk[j] = (__bf16)(p ? v[j].y : v[j].x);
                *(bf16x8*)(slot + (2 * l + p + 1) * 64 + ((wid ^ ((w >> 1) & 3)) << 4)) = pk;
            }
            if (tid < 64) {
                const int side = l >> 5, ch = l & 31;
                const int wg = wbase + (side ? 128 : -1);
                const int m = (wg < 0) ? 3 : ((wg >> 1) & 3);
                const int e = side ? 129 : 0;
                *(__bf16*)(slot + e * 64 + (((ch >> 3) ^ m) << 4) + (ch & 7) * 2) =
                    (__bf16)hval;
            }
            __syncthreads();
        }
    }

    // final row stores
    {
        float* outb = out + (size_t)b * OCH * HW + (size_t)(h0 + BH - 1) * WW + wbase;
#pragma unroll
        for (int nt = 0; nt < 8; ++nt)
#pragma unroll
            for (int r2 = 0; r2 < 4; ++r2)
                outb[(size_t)(wid * 16 + lh * 4 + r2) * HW + nt * 16 + lm] =
                    acc[nt][r2];
    }
}

extern "C" void kernel_launch(void* const* d_in, const int* in_sizes, int n_in,
                              void* d_out, int out_size, void* d_ws, size_t ws_size,
                              hipStream_t stream) {
    const float* x    = (const float*)d_in[0];
    const float* w    = (const float*)d_in[1];
    const float* bias = (const float*)d_in[2];
    float* out = (float*)d_out;

    hipLaunchKernelGGL(conv_fused_kernel, dim3(1024), dim3(256), 0, stream,
                       x, w, bias, out);
}